// Round 11
// baseline (273.662 us; speedup 1.0000x reference)
//
#include <hip/hip_runtime.h>
#include <hip/hip_bf16.h>

// SegmentConv2d: fake-quant-int8 (global for x, per-128-oc-chunk for w) + 3x3 pad1 conv + bias.
// int8 path: quantize to real int8, conv with mfma_i32_16x16x64_i8 (exact int accum),
// scale+bias epilogue.
//
// Shapes: x[8][256][128][128] f32, w[512][256][3][3] f32, bias[512], out[8][512][128][128] f32.
//
// ws layout:
//   [0..63]           : amax[5] (uint bits, written by k_amax2 - no atomics)
//   [64..79]          : 16B zeros (OOB redirect for global_load_lds)
//   [256..13567]      : per-block amax partials float[3328] (x: 0..2047, w: 2048..3199)
//   [16384..)         : qx int8 NHWC  [n][h][w][c]  = 33,554,432 B
//   [16384+32M..)     : qw int8       [r*3+s][oc][c] = 1,179,648 B

typedef int i32x4 __attribute__((ext_vector_type(4)));

__device__ __forceinline__ void llds16(const void* g, void* l) {
    __builtin_amdgcn_global_load_lds(
        (const __attribute__((address_space(1))) void*)g,
        (__attribute__((address_space(3))) void*)l,
        16, 0, 0);
}

__device__ __forceinline__ float f4max(float4 v) {
    return fmaxf(fmaxf(fabsf(v.x), fabsf(v.y)), fmaxf(fabsf(v.z), fabsf(v.w)));
}

// ---------------- amax stage 1: per-block partial maxima (NO atomics) ----------------
__global__ __launch_bounds__(256) void k_amax(const float4* __restrict__ x,
                                              const float4* __restrict__ w4,
                                              float* __restrict__ part) {
    __shared__ float red[4];
    int t = threadIdx.x;
    float m = 0.f;
    if (blockIdx.x < 2048) {
        int tid = blockIdx.x * 256 + t;
        float4 v[16];
#pragma unroll
        for (int k = 0; k < 16; ++k)
            v[k] = x[(size_t)tid + (size_t)k * 524288];
#pragma unroll
        for (int k = 0; k < 16; ++k) m = fmaxf(m, f4max(v[k]));
    } else {
        int b = blockIdx.x - 2048;          // 0..1151
        int chunk = b / 288;
        int tid = (b - chunk * 288) * 256 + t;
        m = f4max(w4[(size_t)chunk * 73728 + tid]);
    }
    for (int off = 32; off > 0; off >>= 1) m = fmaxf(m, __shfl_xor(m, off, 64));
    if ((t & 63) == 0) red[t >> 6] = m;
    __syncthreads();
    if (t == 0)
        part[blockIdx.x] = fmaxf(fmaxf(red[0], red[1]), fmaxf(red[2], red[3]));
}

// ---------------- amax stage 2: reduce partials -> amaxb[0..4] ----------------
__global__ __launch_bounds__(256) void k_amax2(const float* __restrict__ part,
                                               unsigned* __restrict__ amaxb) {
    __shared__ float red[4];
    int t = threadIdx.x;
    float m = 0.f;
#pragma unroll
    for (int k = 0; k < 8; ++k) m = fmaxf(m, part[t + k * 256]);
    for (int off = 32; off > 0; off >>= 1) m = fmaxf(m, __shfl_xor(m, off, 64));
    if ((t & 63) == 0) red[t >> 6] = m;
    __syncthreads();
    if (t == 0)
        amaxb[0] = __float_as_uint(fmaxf(fmaxf(red[0], red[1]), fmaxf(red[2], red[3])));
    // w: one wave per chunk, 288 partials each
    int c = t >> 6, l = t & 63;
    float wm = 0.f;
#pragma unroll
    for (int k = 0; k < 5; ++k) {
        int i = l + k * 64;
        if (i < 288) wm = fmaxf(wm, part[2048 + c * 288 + i]);
    }
    for (int off = 32; off > 0; off >>= 1) wm = fmaxf(wm, __shfl_xor(wm, off, 64));
    if (l == 0) amaxb[1 + c] = __float_as_uint(wm);
}

// ---------------- quantize x : NCHW f32 -> NHWC int8 ----------------
__global__ __launch_bounds__(256) void k_quant_x(const float* __restrict__ x,
                                                 signed char* __restrict__ qx,
                                                 const unsigned* __restrict__ amaxb) {
    float inv = 127.0f / fmaxf(__uint_as_float(amaxb[0]), 1e-12f);
    int row = blockIdx.x;                 // n*128 + h
    int n = row >> 7, h = row & 127;
    int t = threadIdx.x;
    int w4 = t & 31, cg = t >> 5;         // w4: float4 slot along w; cg in [0,8)
    const float* base = x + (size_t)n * 256 * 16384 + (size_t)h * 128 + w4 * 4;
#pragma unroll
    for (int pp = 0; pp < 2; ++pp) {
        int c0 = pp * 128 + cg * 16;
        float4 v[16];
#pragma unroll
        for (int j = 0; j < 16; ++j)
            v[j] = *(const float4*)(base + (size_t)(c0 + j) * 16384);
#pragma unroll
        for (int i = 0; i < 4; ++i) {
            unsigned wds[4];
#pragma unroll
            for (int jg = 0; jg < 4; ++jg) {
                unsigned u = 0;
#pragma unroll
                for (int jj = 0; jj < 4; ++jj) {
                    float f = (&v[jg * 4 + jj].x)[i];
                    int q = (int)fminf(fmaxf(rintf(f * inv), -128.f), 127.f);
                    u |= ((unsigned)(q & 255)) << (8 * jj);
                }
                wds[jg] = u;
            }
            *(uint4*)&qx[(size_t)row * 32768 + (size_t)(w4 * 4 + i) * 256 + c0] =
                make_uint4(wds[0], wds[1], wds[2], wds[3]);
        }
    }
}

// ---------------- quantize w : OIHW f32 -> [rs][oc][c] int8 ----------------
__global__ void k_quant_w(const float* __restrict__ wsrc, signed char* __restrict__ qw,
                          const unsigned* __restrict__ amaxb) {
    int idx = blockIdx.x * 256 + threadIdx.x;   // 131072 = 512 blocks
    int oc = idx >> 8, c = idx & 255;
    float inv = 127.0f / fmaxf(__uint_as_float(amaxb[1 + (oc >> 7)]), 1e-12f);
    const float* src = wsrc + (size_t)idx * 9;
    float v[9];
#pragma unroll
    for (int rs = 0; rs < 9; ++rs) v[rs] = src[rs];
#pragma unroll
    for (int rs = 0; rs < 9; ++rs) {
        float qf = fminf(fmaxf(rintf(v[rs] * inv), -128.f), 127.f);
        qw[((size_t)(rs * 512 + oc)) * 256 + c] = (signed char)(int)qf;
    }
}

// ---------------- conv : implicit GEMM with mfma_i32_16x16x64_i8 ----------------
// Round-11: EXACT round-6 structure (best measured: grid 2048, 4 waves, 128oc x 256px,
// 57.8 KB LDS, 2 blocks/CU, 12 phases, 2 barriers/phase) + ONE change: the s-loop is
// software-pipelined at FRAGMENT level. Round-6 analysis: per-CU MFMA time 78us +
// LDS-port time 68us ~= measured 155us -> the pipes serialize, because each wave does
// [12 ds_read -> lgkmcnt -> 32 MFMA] and co-resident blocks convoy on the shared LDS
// port. Fix: issue ds_reads for s+1 BEFORE the MFMA cluster for s (named double
// buffers, statically unrolled; compiler emits counted lgkmcnt so MFMA(s) doesn't
// wait on reads(s+1)) -> each wave demands LDS port and MFMA pipe simultaneously.
// + setprio(1) around MFMA clusters. +48 VGPR for the double fragments.
__global__ __launch_bounds__(256, 2) void k_conv(
    const signed char* __restrict__ qx, const signed char* __restrict__ qw,
    const signed char* __restrict__ zb, const unsigned* __restrict__ amaxb,
    const float* __restrict__ bias, float* __restrict__ out) {
    __shared__ __align__(16) signed char xs[4 * 8320];      // 33280 B
    __shared__ __align__(16) signed char wt[3 * 128 * 64];  // 24576 B
    int orig = blockIdx.x;                      // 0..2047, nwg % 8 == 0
    int wgid = (orig & 7) * 256 + (orig >> 3);  // bijective XCD swizzle
    int rowpair = wgid >> 2, ocg = wgid & 3;    // ocg: 128-oc group == weight chunk
    int n = rowpair >> 6;                       // 64 rowpairs per image
    int h0 = (rowpair & 63) * 2;
    int t = threadIdx.x, wid = t >> 6, lane = t & 63;
    int lp = lane & 15, hi = lane >> 4;
    int rowsel = wid >> 1, whalf = wid & 1;

    i32x4 acc[8][4] = {};

    auto stageX = [&](int cb) {
        // xs: 4 rows x 130 w x 4 q4 = 2080 x 16B, lane-linear LDS dest
#pragma unroll
        for (int i = 0; i < 9; ++i) {
            int idx = t + i * 256;
            if (idx < 2080) {
                int rowk = idx / 520;
                int j = idx - rowk * 520;
                int wr = j >> 2, q4 = j & 3;
                int wg = wr - 1;
                int hh = h0 - 1 + rowk;
                int q4s = q4 ^ ((wr >> 1) & 3);
                const signed char* src = (hh >= 0 && hh < 128 && wg >= 0 && wg < 128)
                    ? qx + (size_t)(n * 128 + hh) * 32768 + wg * 256 + cb * 64 + q4s * 16
                    : zb;
                llds16(src, xs + (size_t)(i * 256 + wid * 64) * 16);
            }
        }
    };
    auto stageW = [&](int cb, int r) {
        // wt: 3 s x 128 oc x 4 q4 = 1536 x 16B
#pragma unroll
        for (int i = 0; i < 6; ++i) {
            int idx = t + i * 256;       // 0..1535
            int s = idx >> 9, rem = idx & 511;
            int oc = rem >> 2, q4 = rem & 3;
            int q4s = q4 ^ ((oc >> 1) & 3);
            const signed char* src = qw
                + (size_t)((r * 3 + s) * 512 + ocg * 128 + oc) * 256 + cb * 64 + q4s * 16;
            llds16(src, wt + (size_t)(i * 256 + wid * 64) * 16);
        }
    };
    auto rdA = [&](int s, i32x4* a) {
#pragma unroll
        for (int mf = 0; mf < 8; ++mf) {
            int ocr = mf * 16 + lp;
            a[mf] = *(const i32x4*)&wt[s * 8192 + ocr * 64
                                       + ((hi ^ ((ocr >> 1) & 3)) << 4)];
        }
    };
    auto rdB = [&](int s, int rowk, i32x4* b) {
#pragma unroll
        for (int nf = 0; nf < 4; ++nf) {
            int slot = whalf * 64 + nf * 16 + lp + s;
            b[nf] = *(const i32x4*)&xs[rowk * 8320 + slot * 64
                                       + ((hi ^ ((slot >> 1) & 3)) << 4)];
        }
    };
    auto domm = [&](i32x4* a, i32x4* b) {
        __builtin_amdgcn_s_setprio(1);
#pragma unroll
        for (int mf = 0; mf < 8; ++mf)
#pragma unroll
            for (int nf = 0; nf < 4; ++nf)
                acc[mf][nf] = __builtin_amdgcn_mfma_i32_16x16x64_i8(
                    a[mf], b[nf], acc[mf][nf], 0, 0, 0);
        __builtin_amdgcn_s_setprio(0);
    };

    for (int cb = 0; cb < 4; ++cb) {
#pragma unroll
        for (int r = 0; r < 3; ++r) {
            if (r == 0) stageX(cb);
            stageW(cb, r);
            __syncthreads();               // staging landed (implicit vmcnt drain)
            int rowk = r + rowsel;
            // s-pipelined fragment double-buffer: reads(s+1) issued before MFMA(s)
            i32x4 aA[8], bA[4], aB[8], bB[4];
            rdA(0, aA); rdB(0, rowk, bA);
            rdA(1, aB); rdB(1, rowk, bB);
            domm(aA, bA);                  // s=0 (overlaps s=1 reads in flight)
            rdA(2, aA); rdB(2, rowk, bA);
            domm(aB, bB);                  // s=1 (overlaps s=2 reads in flight)
            domm(aA, bA);                  // s=2
            __syncthreads();               // fragment reads done -> wt/xs reusable
        }
    }

    float sx = fmaxf(__uint_as_float(amaxb[0]), 1e-12f) / 127.0f;
    float sw = fmaxf(__uint_as_float(amaxb[1 + ocg]), 1e-12f) / 127.0f;
    float sc = sx * sw;
    int h = h0 + rowsel;
#pragma unroll
    for (int mf = 0; mf < 8; ++mf)
#pragma unroll
        for (int nf = 0; nf < 4; ++nf)
#pragma unroll
            for (int j = 0; j < 4; ++j) {
                int oc = ocg * 128 + mf * 16 + hi * 4 + j;
                int px = whalf * 64 + nf * 16 + lp;
                out[((size_t)(n * 512 + oc) * 128 + h) * 128 + px] =
                    (float)acc[mf][nf][j] * sc + bias[oc];
            }
}

extern "C" void kernel_launch(void* const* d_in, const int* in_sizes, int n_in,
                              void* d_out, int out_size, void* d_ws, size_t ws_size,
                              hipStream_t stream) {
    const float* x    = (const float*)d_in[0];
    const float* wgt  = (const float*)d_in[1];
    const float* bias = (const float*)d_in[2];
    float* out = (float*)d_out;

    unsigned* amaxb = (unsigned*)d_ws;
    float* part = (float*)((char*)d_ws + 256);
    signed char* qx = (signed char*)d_ws + 16384;
    signed char* qw = (signed char*)d_ws + 16384 + 33554432;
    const signed char* zb = (const signed char*)d_ws + 64;   // 16B zeros for OOB redirect

    hipMemsetAsync(d_ws, 0, 256, stream);   // zb zeros (amax slots overwritten by k_amax2)

    k_amax<<<3200, 256, 0, stream>>>((const float4*)x, (const float4*)wgt, part);
    k_amax2<<<1, 256, 0, stream>>>(part, amaxb);
    k_quant_x<<<1024, 256, 0, stream>>>(x, qx, amaxb);
    k_quant_w<<<512, 256, 0, stream>>>(wgt, qw, amaxb);
    k_conv<<<dim3(2048), 256, 0, stream>>>(qx, qw, zb, amaxb, bias, out);
}

// Round 12
// 262.858 us; speedup vs baseline: 1.0411x; 1.0411x over previous
//
#include <hip/hip_runtime.h>
#include <hip/hip_bf16.h>

// SegmentConv2d: fake-quant-int8 (global for x, per-128-oc-chunk for w) + 3x3 pad1 conv + bias.
// int8 path: quantize to real int8, conv with mfma_i32_16x16x64_i8 (exact int accum),
// scale+bias epilogue.
//
// Shapes: x[8][256][128][128] f32, w[512][256][3][3] f32, bias[512], out[8][512][128][128] f32.
//
// ws layout:
//   [0..63]           : amax[5] (uint bits, written by k_amax2 - no atomics)
//   [64..79]          : 16B zeros (OOB redirect for global_load_lds)
//   [256..13567]      : per-block amax partials float[3328] (x: 0..2047, w: 2048..3199)
//   [16384..)         : qx int8 NHWC  [n][h][w][c]  = 33,554,432 B
//   [16384+32M..)     : qw int8       [r*3+s][oc][c] = 1,179,648 B

typedef int i32x4 __attribute__((ext_vector_type(4)));

__device__ __forceinline__ void llds16(const void* g, void* l) {
    __builtin_amdgcn_global_load_lds(
        (const __attribute__((address_space(1))) void*)g,
        (__attribute__((address_space(3))) void*)l,
        16, 0, 0);
}

__device__ __forceinline__ float f4max(float4 v) {
    return fmaxf(fmaxf(fabsf(v.x), fabsf(v.y)), fmaxf(fabsf(v.z), fabsf(v.w)));
}

__device__ __forceinline__ void barrier_f() {
    asm volatile("" ::: "memory");
    __builtin_amdgcn_s_barrier();
    asm volatile("" ::: "memory");
}

// ---------------- amax stage 1: per-block partial maxima (NO atomics) ----------------
__global__ __launch_bounds__(256) void k_amax(const float4* __restrict__ x,
                                              const float4* __restrict__ w4,
                                              float* __restrict__ part) {
    __shared__ float red[4];
    int t = threadIdx.x;
    float m = 0.f;
    if (blockIdx.x < 2048) {
        int tid = blockIdx.x * 256 + t;
        float4 v[16];
#pragma unroll
        for (int k = 0; k < 16; ++k)
            v[k] = x[(size_t)tid + (size_t)k * 524288];
#pragma unroll
        for (int k = 0; k < 16; ++k) m = fmaxf(m, f4max(v[k]));
    } else {
        int b = blockIdx.x - 2048;          // 0..1151
        int chunk = b / 288;
        int tid = (b - chunk * 288) * 256 + t;
        m = f4max(w4[(size_t)chunk * 73728 + tid]);
    }
    for (int off = 32; off > 0; off >>= 1) m = fmaxf(m, __shfl_xor(m, off, 64));
    if ((t & 63) == 0) red[t >> 6] = m;
    __syncthreads();
    if (t == 0)
        part[blockIdx.x] = fmaxf(fmaxf(red[0], red[1]), fmaxf(red[2], red[3]));
}

// ---------------- amax stage 2: reduce partials -> amaxb[0..4] ----------------
__global__ __launch_bounds__(256) void k_amax2(const float* __restrict__ part,
                                               unsigned* __restrict__ amaxb) {
    __shared__ float red[4];
    int t = threadIdx.x;
    float m = 0.f;
#pragma unroll
    for (int k = 0; k < 8; ++k) m = fmaxf(m, part[t + k * 256]);
    for (int off = 32; off > 0; off >>= 1) m = fmaxf(m, __shfl_xor(m, off, 64));
    if ((t & 63) == 0) red[t >> 6] = m;
    __syncthreads();
    if (t == 0)
        amaxb[0] = __float_as_uint(fmaxf(fmaxf(red[0], red[1]), fmaxf(red[2], red[3])));
    // w: one wave per chunk, 288 partials each
    int c = t >> 6, l = t & 63;
    float wm = 0.f;
#pragma unroll
    for (int k = 0; k < 5; ++k) {
        int i = l + k * 64;
        if (i < 288) wm = fmaxf(wm, part[2048 + c * 288 + i]);
    }
    for (int off = 32; off > 0; off >>= 1) wm = fmaxf(wm, __shfl_xor(wm, off, 64));
    if (l == 0) amaxb[1 + c] = __float_as_uint(wm);
}

// ---------------- quantize x : NCHW f32 -> NHWC int8 ----------------
__global__ __launch_bounds__(256) void k_quant_x(const float* __restrict__ x,
                                                 signed char* __restrict__ qx,
                                                 const unsigned* __restrict__ amaxb) {
    float inv = 127.0f / fmaxf(__uint_as_float(amaxb[0]), 1e-12f);
    int row = blockIdx.x;                 // n*128 + h
    int n = row >> 7, h = row & 127;
    int t = threadIdx.x;
    int w4 = t & 31, cg = t >> 5;         // w4: float4 slot along w; cg in [0,8)
    const float* base = x + (size_t)n * 256 * 16384 + (size_t)h * 128 + w4 * 4;
#pragma unroll
    for (int pp = 0; pp < 2; ++pp) {
        int c0 = pp * 128 + cg * 16;
        float4 v[16];
#pragma unroll
        for (int j = 0; j < 16; ++j)
            v[j] = *(const float4*)(base + (size_t)(c0 + j) * 16384);
#pragma unroll
        for (int i = 0; i < 4; ++i) {
            unsigned wds[4];
#pragma unroll
            for (int jg = 0; jg < 4; ++jg) {
                unsigned u = 0;
#pragma unroll
                for (int jj = 0; jj < 4; ++jj) {
                    float f = (&v[jg * 4 + jj].x)[i];
                    int q = (int)fminf(fmaxf(rintf(f * inv), -128.f), 127.f);
                    u |= ((unsigned)(q & 255)) << (8 * jj);
                }
                wds[jg] = u;
            }
            *(uint4*)&qx[(size_t)row * 32768 + (size_t)(w4 * 4 + i) * 256 + c0] =
                make_uint4(wds[0], wds[1], wds[2], wds[3]);
        }
    }
}

// ---------------- quantize w : OIHW f32 -> [rs][oc][c] int8 ----------------
__global__ void k_quant_w(const float* __restrict__ wsrc, signed char* __restrict__ qw,
                          const unsigned* __restrict__ amaxb) {
    int idx = blockIdx.x * 256 + threadIdx.x;   // 131072 = 512 blocks
    int oc = idx >> 8, c = idx & 255;
    float inv = 127.0f / fmaxf(__uint_as_float(amaxb[1 + (oc >> 7)]), 1e-12f);
    const float* src = wsrc + (size_t)idx * 9;
    float v[9];
#pragma unroll
    for (int rs = 0; rs < 9; ++rs) v[rs] = src[rs];
#pragma unroll
    for (int rs = 0; rs < 9; ++rs) {
        float qf = fminf(fmaxf(rintf(v[rs] * inv), -128.f), 127.f);
        qw[((size_t)(rs * 512 + oc)) * 256 + c] = (signed char)(int)qf;
    }
}

// ---------------- conv : implicit GEMM with mfma_i32_16x16x64_i8 ----------------
// Round-12: the untried cell -- 1 wave/SIMD with 512-VGPR budget.
// grid 2048 (XCD swizzle), block 256 = 4 waves, launch_bounds(256,1) -> 1 block/CU,
// LDS fully double-buffered (116 KB): xs2[2][4 rows][130 slots][64c], wt2[2][3s][128oc][64c].
// Tile 128oc x 2 rows x 128px (= round-6's tile); wave = 128oc x 64px (8mf x 4nf).
// 12 phases (cb x r). Per phase p:
//   C0 barrier (all waves done reading p-1's buffers -> safe to overwrite)
//   issue stage(p+1) [uniform 6 or 14 insts/thread]
//   s_waitcnt vmcnt(N), N = count(stage(p+1)) -> stage(p) landed, p+1 stays in flight
//   C1 barrier (stage(p) landed in all waves)
//   compute(p): fragment-level double-buffered s-pipeline (reads(s+1) before MFMA(s)).
// Why this works where r4..r11 failed: round-6's 155us = MFMA(78) + LDS(69) SERIAL
// (convoying waves do read-burst then MFMA-burst in lockstep). Decoupling needs the
// SAME wave to demand both pipes -> +96 VGPR frag dbuf -> needs the 512-VGPR budget
// that only 1 wave/SIMD provides (r11 spilled at the 256 cap: FETCH/WRITE +70MB).
// One wave/SIMD saturates the MFMA pipe (independent acc chains); prefetch distance
// = one full phase (~2000 cy) >> HBM latency.
__global__ __launch_bounds__(256, 1) void k_conv(
    const signed char* __restrict__ qx, const signed char* __restrict__ qw,
    const signed char* __restrict__ zb, const unsigned* __restrict__ amaxb,
    const float* __restrict__ bias, float* __restrict__ out) {
    __shared__ __align__(16) signed char xs2[2][4 * 8320];   // 66560 B
    __shared__ __align__(16) signed char wt2[2][3 * 8192];   // 49152 B (115712 total)
    int orig = blockIdx.x;                      // 0..2047, nwg % 8 == 0
    int wgid = (orig & 7) * 256 + (orig >> 3);  // bijective XCD swizzle
    int rowpair = wgid >> 2, ocg = wgid & 3;    // ocg: 128-oc group == weight chunk
    int n = rowpair >> 6;                       // 64 rowpairs per image
    int h0 = (rowpair & 63) * 2;
    int t = threadIdx.x, wid = t >> 6, lane = t & 63;
    int lp = lane & 15, hi = lane >> 4;
    int rowsel = wid >> 1, whalf = wid & 1;

    i32x4 acc[8][4] = {};

    auto stageX = [&](int cb, int buf) {        // 4 rows x 2 insts = 8 insts/thread
#pragma unroll
        for (int rowk = 0; rowk < 4; ++rowk) {
            int hh = h0 - 1 + rowk;
#pragma unroll
            for (int i = 0; i < 2; ++i) {
                int idx = t + i * 256;          // 0..511: w = idx>>2, q4 = idx&3
                int w = idx >> 2, q4 = idx & 3;
                int q4s = q4 ^ (((w + 1) >> 1) & 3);   // slot = w+1 swizzle inverse
                const signed char* src = (hh >= 0 && hh < 128)
                    ? qx + (size_t)(n * 128 + hh) * 32768 + w * 256 + cb * 64 + q4s * 16
                    : zb;
                llds16(src, &xs2[buf][0] + rowk * 8320 + 64 + (size_t)idx * 16);
            }
        }
    };
    auto stageW = [&](int cb, int r, int buf) { // 6 insts/thread
#pragma unroll
        for (int i = 0; i < 6; ++i) {
            int idx = t + i * 256;              // 0..1535
            int s = idx >> 9, rem = idx & 511;
            int oc = rem >> 2, q4 = rem & 3;
            int q4s = q4 ^ ((oc >> 1) & 3);
            const signed char* src = qw
                + (size_t)((r * 3 + s) * 512 + ocg * 128 + oc) * 256 + cb * 64 + q4s * 16;
            llds16(src, &wt2[buf][0] + (size_t)idx * 16);
        }
    };
    auto rdA = [&](int wb, int s, i32x4* a) {
#pragma unroll
        for (int mf = 0; mf < 8; ++mf) {
            int ocr = mf * 16 + lp;
            a[mf] = *(const i32x4*)&wt2[wb][s * 8192 + ocr * 64
                                           + ((hi ^ ((ocr >> 1) & 3)) << 4)];
        }
    };
    auto rdB = [&](int xb, int s, int rowk, i32x4* b) {
#pragma unroll
        for (int nf = 0; nf < 4; ++nf) {
            int slot = whalf * 64 + nf * 16 + lp + s;
            b[nf] = *(const i32x4*)&xs2[xb][rowk * 8320 + slot * 64
                                            + ((hi ^ ((slot >> 1) & 3)) << 4)];
        }
    };
    auto domm = [&](i32x4* a, i32x4* b) {
#pragma unroll
        for (int mf = 0; mf < 8; ++mf)
#pragma unroll
            for (int nf = 0; nf < 4; ++nf)
                acc[mf][nf] = __builtin_amdgcn_mfma_i32_16x16x64_i8(
                    a[mf], b[nf], acc[mf][nf], 0, 0, 0);
    };

    // prologue: zero w-halo slots (slot 0,129 of each row, both buffers; staging
    // never touches them), issue stage(0).
    if (t < 64) {
        int buf = t >> 5, rem = t & 31;
        int row = rem >> 3, side = (rem >> 2) & 1, q = rem & 3;
        *(i32x4*)&xs2[buf][row * 8320 + (side ? 129 : 0) * 64 + q * 16] =
            i32x4{0, 0, 0, 0};
    }
    stageX(0, 0);
    stageW(0, 0, 0);
    asm volatile("s_waitcnt lgkmcnt(0)" ::: "memory");   // halo zeros done

#define PHASE(P, NW)                                                          \
    {                                                                         \
        constexpr int cb_ = (P) / 3, r_ = (P) % 3;                            \
        barrier_f();                   /* C0: done reading p-1 buffers */     \
        if ((P) < 11) {                                                       \
            constexpr int cbn = ((P) + 1) / 3, rn = ((P) + 1) % 3;            \
            if (rn == 0) stageX(cbn, cbn & 1);                                \
            stageW(cbn, rn, ((P) + 1) & 1);                                   \
        }                                                                     \
        asm volatile("s_waitcnt vmcnt(" #NW ")" ::: "memory");                \
        barrier_f();                   /* C1: stage(P) landed everywhere */   \
        {                                                                     \
            const int rowk = r_ + rowsel;                                     \
            i32x4 aA[8], bA[4], aB[8], bB[4];                                 \
            rdA((P) & 1, 0, aA); rdB(cb_ & 1, 0, rowk, bA);                   \
            rdA((P) & 1, 1, aB); rdB(cb_ & 1, 1, rowk, bB);                   \
            domm(aA, bA);              /* s=0, s=1 reads in flight */         \
            rdA((P) & 1, 2, aA); rdB(cb_ & 1, 2, rowk, bA);                   \
            domm(aB, bB);              /* s=1, s=2 reads in flight */         \
            domm(aA, bA);              /* s=2 */                              \
        }                                                                     \
    }

    // N = inst count of stage(P+1): 14 when (P+1)%3==0 (X+W), else 6 (W only), 0 at end
    PHASE(0, 6)  PHASE(1, 6)  PHASE(2, 14) PHASE(3, 6)  PHASE(4, 6)  PHASE(5, 14)
    PHASE(6, 6)  PHASE(7, 6)  PHASE(8, 14) PHASE(9, 6)  PHASE(10, 6) PHASE(11, 0)
#undef PHASE

    float sx = fmaxf(__uint_as_float(amaxb[0]), 1e-12f) / 127.0f;
    float sw = fmaxf(__uint_as_float(amaxb[1 + ocg]), 1e-12f) / 127.0f;
    float sc = sx * sw;
    int h = h0 + rowsel;
#pragma unroll
    for (int mf = 0; mf < 8; ++mf)
#pragma unroll
        for (int nf = 0; nf < 4; ++nf)
#pragma unroll
            for (int j = 0; j < 4; ++j) {
                int oc = ocg * 128 + mf * 16 + hi * 4 + j;
                int px = whalf * 64 + nf * 16 + lp;
                out[((size_t)(n * 512 + oc) * 128 + h) * 128 + px] =
                    (float)acc[mf][nf][j] * sc + bias[oc];
            }
}

extern "C" void kernel_launch(void* const* d_in, const int* in_sizes, int n_in,
                              void* d_out, int out_size, void* d_ws, size_t ws_size,
                              hipStream_t stream) {
    const float* x    = (const float*)d_in[0];
    const float* wgt  = (const float*)d_in[1];
    const float* bias = (const float*)d_in[2];
    float* out = (float*)d_out;

    unsigned* amaxb = (unsigned*)d_ws;
    float* part = (float*)((char*)d_ws + 256);
    signed char* qx = (signed char*)d_ws + 16384;
    signed char* qw = (signed char*)d_ws + 16384 + 33554432;
    const signed char* zb = (const signed char*)d_ws + 64;   // 16B zeros for OOB redirect

    hipMemsetAsync(d_ws, 0, 256, stream);   // zb zeros (amax slots overwritten by k_amax2)

    k_amax<<<3200, 256, 0, stream>>>((const float4*)x, (const float4*)wgt, part);
    k_amax2<<<1, 256, 0, stream>>>(part, amaxb);
    k_quant_x<<<1024, 256, 0, stream>>>(x, qx, amaxb);
    k_quant_w<<<512, 256, 0, stream>>>(wgt, qw, amaxb);
    k_conv<<<dim3(2048), 256, 0, stream>>>(qx, qw, zb, amaxb, bias, out);
}